// Round 1
// baseline (33176.825 us; speedup 1.0000x reference)
//
#include <hip/hip_runtime.h>
#include <math.h>

#define TID ((int)threadIdx.x)

namespace {

constexpr int Bn = 256, Tn = 256, Dn = 256, Hn = 512, Sn = 32;
constexpr int NOS = 32;   // H-slices (blocks per team)
constexpr int JH  = 16;   // h-cols per block  (Hn/NOS)
constexpr int BC  = 32;   // batch rows per block (Bn/8 teams)
constexpr int BTS = Bn * Tn * Sn;          // 2097152
constexpr int OFF_ST   = 0;
constexpr int OFF_PRM  = BTS;
constexpr int OFF_PRLV = 2 * BTS;
constexpr int OFF_PM   = 3 * BTS;
constexpr int OFF_PLV  = 4 * BTS;
constexpr int OFF_HF   = 5 * BTS;          // 10485760
constexpr int BARS_PER_TEAM = 1056;        // need 1026

struct P {
  const float *latent, *hidden, *eps;
  const float *wih0, *whh0, *bih0, *bhh0;
  const float *wih1, *whh1, *bih1, *bhh1;
  const float *wpost1, *bpost1, *wpost2, *bpost2;
  const float *wprior1, *bprior1, *wprior2, *bprior2;
  float *out;
  float *h0, *h1, *ph, *qh, *st;   // workspace views
  unsigned *bars;
};

__device__ __forceinline__ void team_bar(unsigned* slot) {
  __syncthreads();
  if (TID == 0) {
    __threadfence();  // publish this block's ws writes device-wide
    __hip_atomic_fetch_add(slot, 1u, __ATOMIC_RELEASE, __HIP_MEMORY_SCOPE_AGENT);
    while (__hip_atomic_load(slot, __ATOMIC_ACQUIRE, __HIP_MEMORY_SCOPE_AGENT) < 32u) {
      __builtin_amdgcn_s_sleep(1);
    }
  }
  __syncthreads();
}

// Stage 48 W-rows {g*512 + os*16 + j} x 64(32) k into transposed LDS tile wT[kk][g*16+j].
template<int SHIFT>  // k-quads per row: 1<<SHIFT (16 for klen=64, 8 for klen=32)
__device__ __forceinline__ void stageW48(float (*wT)[52], const float* __restrict__ W,
                                         int K, int k0, int os) {
  constexpr int KQ = 1 << SHIFT;
  const int nf4 = 48 * KQ;
  for (int v = TID; v < nf4; v += 512) {
    const int row = v >> SHIFT;
    const int kq  = v & (KQ - 1);
    const int g = row >> 4, j = row & 15;
    const float4 w = *(const float4*)(W + (size_t)(g * Hn + os * JH + j) * K + k0 + (kq << 2));
    const int kk = kq << 2;
    wT[kk + 0][row] = w.x; wT[kk + 1][row] = w.y;
    wT[kk + 2][row] = w.z; wT[kk + 3][row] = w.w;
  }
}

// Stage 16 W-rows {wrow0 + j} x 64 k into wT[kk][co + j].
__device__ __forceinline__ void stageW16(float (*wT)[52], int co, const float* __restrict__ W,
                                         int K, int wrow0, int k0) {
  for (int v = TID; v < 256; v += 512) {
    const int j = v >> 4;
    const int kq = v & 15;
    const float4 w = *(const float4*)(W + (size_t)(wrow0 + j) * K + k0 + (kq << 2));
    const int kk = kq << 2;
    wT[kk + 0][co + j] = w.x; wT[kk + 1][co + j] = w.y;
    wT[kk + 2][co + j] = w.z; wT[kk + 3][co + j] = w.w;
  }
}

// Stage 32 activation rows x klen k into xc[row][kk].
template<int SHIFT>
__device__ __forceinline__ void stageX(float (*xc)[68], const float* __restrict__ src,
                                       int rstride, int k0, int bg) {
  constexpr int KQ = 1 << SHIFT;
  const int nf4 = 32 * KQ;
  for (int v = TID; v < nf4; v += 512) {
    const int row = v >> SHIFT;
    const int kq = v & (KQ - 1);
    const float4 x = *(const float4*)(src + (size_t)(bg * BC + row) * rstride + k0 + (kq << 2));
    *(float4*)&xc[row][kq << 2] = x;
  }
}

// 2 rows x (3 gates x j-pair) accumulate over k-window [ka,kb). v in [0,128).
__device__ __forceinline__ void ghAccum(float* acc, const float (*wT)[52], const float (*xc)[68],
                                        int v, int ka, int kb) {
  const int rp = v >> 3, jp = v & 7;
  const int r0 = rp * 2, c0 = jp * 2;
  #pragma unroll 4
  for (int kk = ka; kk < kb; kk += 2) {
    const float2 xa = *(const float2*)&xc[r0][kk];
    const float2 xb = *(const float2*)&xc[r0 + 1][kk];
    #pragma unroll
    for (int g = 0; g < 3; g++) {
      const float2 w0 = *(const float2*)&wT[kk][g * 16 + c0];
      const float2 w1 = *(const float2*)&wT[kk + 1][g * 16 + c0];
      acc[g * 4 + 0] += xa.x * w0.x + xa.y * w1.x;
      acc[g * 4 + 1] += xa.x * w0.y + xa.y * w1.y;
      acc[g * 4 + 2] += xb.x * w0.x + xb.y * w1.x;
      acc[g * 4 + 3] += xb.x * w0.y + xb.y * w1.y;
    }
  }
}

// 2 rows x j-pair (16-col matmuls: prior1 / post1).
__device__ __forceinline__ void qAccum(float* acc, const float (*wT)[52], int co,
                                       const float (*xc)[68], int v, int ka, int kb) {
  const int rp = v >> 3, jp = v & 7;
  const int r0 = rp * 2, c0 = jp * 2;
  #pragma unroll 4
  for (int kk = ka; kk < kb; kk += 2) {
    const float2 xa = *(const float2*)&xc[r0][kk];
    const float2 xb = *(const float2*)&xc[r0 + 1][kk];
    const float2 w0 = *(const float2*)&wT[kk][co + c0];
    const float2 w1 = *(const float2*)&wT[kk + 1][co + c0];
    acc[0] += xa.x * w0.x + xa.y * w1.x;
    acc[1] += xa.x * w0.y + xa.y * w1.y;
    acc[2] += xb.x * w0.x + xb.y * w1.x;
    acc[3] += xb.x * w0.y + xb.y * w1.y;
  }
}

__device__ __forceinline__ float dotChunk(const float* __restrict__ x, const float* __restrict__ w,
                                          int k0, int n) {
  float d = 0.f;
  #pragma unroll 4
  for (int k = k0; k < k0 + n; k += 4) {
    const float4 a = *(const float4*)(x + k);
    const float4 b = *(const float4*)(w + k);
    d += a.x * b.x + a.y * b.y + a.z * b.z + a.w * b.w;
  }
  return d;
}

__global__ __launch_bounds__(512, 1) void rssm_kernel(P p) {
  __shared__ float wT0[64][52];
  __shared__ float wT1[64][52];
  __shared__ float xcA[32][68];
  __shared__ float xcB[32][68];
  __shared__ float ghA[32][48];        // gh of GRU0 (B -> C), bias included
  __shared__ float ghB[32][48];        // gh of GRU1 (B -> D)
  __shared__ float part[4][32][48];    // k-split partials (C/D; reused flat in E)
  __shared__ float ppq[2][2][32];      // posterior-head partials [c][kseg][r]
  __shared__ float prq[2][2][32];      // prior-head partials
  __shared__ float ppv[32][2];         // combined pm/plv

  const int bg = blockIdx.x & 7;       // team (same-mod-8 -> likely same XCD)
  const int os = blockIdx.x >> 3;      // h-slice
  unsigned* bars = p.bars + bg * BARS_PER_TEAM;
  int bar_i = 0;

  const int wv = TID >> 6;             // wave 0..7
  const int v  = TID & 127;            // index within wave-pair
  const int wp = TID >> 7;             // wave-pair 0..3

  // ---- prologue: copy hidden -> h0/h1 (own slice) ----
  {
    const int r = TID >> 4, j = TID & 15;
    const int b = bg * BC + r; const int col = os * JH + j;
    p.h0[b * Hn + col] = p.hidden[b * Hn + col];
    p.h1[b * Hn + col] = p.hidden[Bn * Hn + b * Hn + col];
  }
  team_bar(&bars[bar_i++]);

  // ---- phase E: qh = relu(h1@wprior1^T+b) ; ph = relu([h1,x_tnext]@wpost1^T+b) ----
  auto phaseE = [&](int tnext) {
    float acc[4] = {0.f, 0.f, 0.f, 0.f};
    const bool do_ph = (tnext < Tn);
    const int nch = do_ph ? 12 : 8;
    for (int c = 0; c < nch; c++) {
      const int k0 = c << 6;
      if (c < 8) {
        stageW16(wT0, 0, p.wprior1, Hn, os * JH, k0);
        stageX<4>(xcA, p.h1, Hn, k0, bg);
      } else {
        stageX<4>(xcA, p.latent + (size_t)tnext * Dn, Tn * Dn, k0 - Hn, bg);
      }
      if (do_ph) stageW16(wT0, 16, p.wpost1, Hn + Dn, os * JH, k0);
      __syncthreads();
      if (wp < 2) { if (c < 8) qAccum(acc, wT0, 0, xcA, v, wp * 32, wp * 32 + 32); }
      else if (do_ph) qAccum(acc, wT0, 16, xcA, v, (wp - 2) * 32, (wp - 2) * 32 + 32);
      __syncthreads();
    }
    float* pE = &part[0][0][0];  // [4][32][16]
    {
      const int rp = v >> 3, jp = v & 7;
      pE[(wp * 32 + rp * 2    ) * 16 + jp * 2    ] = acc[0];
      pE[(wp * 32 + rp * 2    ) * 16 + jp * 2 + 1] = acc[1];
      pE[(wp * 32 + rp * 2 + 1) * 16 + jp * 2    ] = acc[2];
      pE[(wp * 32 + rp * 2 + 1) * 16 + jp * 2 + 1] = acc[3];
    }
    __syncthreads();
    {
      const int r = TID >> 4, j = TID & 15;
      const int b = bg * BC + r; const int col = os * JH + j;
      const float qv = pE[r * 16 + j] + pE[(32 + r) * 16 + j] + p.bprior1[col];
      p.qh[b * Hn + col] = fmaxf(qv, 0.f);
      if (do_ph) {
        const float pv = pE[(64 + r) * 16 + j] + pE[(96 + r) * 16 + j] + p.bpost1[col];
        p.ph[b * Hn + col] = fmaxf(pv, 0.f);
      }
    }
    __syncthreads();
  };

  // ---- phase B: pp->stoch, gh0, gh1, prior-head(t-1) ----
  auto phaseB = [&](int t) {
    float acc[12] = {0,0,0,0,0,0,0,0,0,0,0,0};
    float dacc = 0.f;
    const int ll = TID & 127;
    const int r_ = ll & 31, cc_ = (ll >> 5) & 1, ks_ = ll >> 6;
    for (int c = 0; c < 8; c++) {
      const int k0 = c << 6;
      stageW48<4>(wT0, p.whh0, Hn, k0, os);
      stageW48<4>(wT1, p.whh1, Hn, k0, os);
      stageX<4>(xcA, p.h0, Hn, k0, bg);
      stageX<4>(xcB, p.h1, Hn, k0, bg);
      __syncthreads();
      if (wv < 2)      ghAccum(acc, wT0, xcA, v, 0, 64);
      else if (wv < 4) ghAccum(acc, wT1, xcB, v, 0, 64);
      else if (wv < 6)
        dacc += dotChunk(p.ph + (size_t)(bg * BC + r_) * Hn,
                         p.wpost2 + (size_t)(os + 32 * cc_) * Hn, ks_ * 256 + c * 32, 32);
      else if (t >= 1)
        dacc += dotChunk(p.qh + (size_t)(bg * BC + r_) * Hn,
                         p.wprior2 + (size_t)(os + 32 * cc_) * Hn, ks_ * 256 + c * 32, 32);
      __syncthreads();
    }
    if (wv < 4) {
      const int rp = v >> 3, jp = v & 7;
      float (*gh)[48] = (wv < 2) ? ghA : ghB;
      const float* bias = (wv < 2) ? p.bhh0 : p.bhh1;
      #pragma unroll
      for (int g = 0; g < 3; g++) {
        const int col = os * JH + jp * 2;
        gh[rp * 2    ][g * 16 + jp * 2    ] = acc[g * 4 + 0] + bias[g * Hn + col];
        gh[rp * 2    ][g * 16 + jp * 2 + 1] = acc[g * 4 + 1] + bias[g * Hn + col + 1];
        gh[rp * 2 + 1][g * 16 + jp * 2    ] = acc[g * 4 + 2] + bias[g * Hn + col];
        gh[rp * 2 + 1][g * 16 + jp * 2 + 1] = acc[g * 4 + 3] + bias[g * Hn + col + 1];
      }
    } else if (wv < 6) {
      ppq[cc_][ks_][r_] = dacc;
    } else if (t >= 1) {
      prq[cc_][ks_][r_] = dacc;
    }
    __syncthreads();
    if (TID < 64) {
      const int r = TID & 31, cc = TID >> 5;
      ppv[r][cc] = ppq[cc][0][r] + ppq[cc][1][r] + p.bpost2[os + 32 * cc];
    } else if (TID < 128 && t >= 1) {
      const int u = TID - 64; const int r = u & 31, cc = u >> 5;
      const float val = prq[cc][0][r] + prq[cc][1][r] + p.bprior2[os + 32 * cc];
      p.out[(cc ? OFF_PRLV : OFF_PRM) + (size_t)(bg * BC + r) * (Tn * Sn) + (t - 1) * Sn + os] = val;
    }
    __syncthreads();
    if (TID < 32) {
      const int r = TID; const int b = bg * BC + r;
      const float pm = ppv[r][0], plv = ppv[r][1];
      const float e = p.eps[(size_t)b * (Tn * Sn) + t * Sn + os];
      const float sv = pm + e * expf(0.5f * plv);
      p.st[b * Sn + os] = sv;
      p.out[OFF_ST  + (size_t)b * (Tn * Sn) + t * Sn + os] = sv;
      p.out[OFF_PM  + (size_t)b * (Tn * Sn) + t * Sn + os] = pm;
      p.out[OFF_PLV + (size_t)b * (Tn * Sn) + t * Sn + os] = plv;
    }
    __syncthreads();
  };

  // ---- phase C/D: gi = X@wih^T (k-split over wave-pairs), then GRU combine ----
  auto phaseGRU = [&](const float* W, const float* bih, float (*ghL)[48], float* hbuf,
                      bool layer0, int t) {
    float acc[12] = {0,0,0,0,0,0,0,0,0,0,0,0};
    const int nch = layer0 ? 5 : 8;
    for (int c = 0; c < nch; c++) {
      const int k0 = c << 6;
      int klen;
      if (layer0) {
        if (c < 4) { stageW48<4>(wT0, W, Dn + Sn, k0, os);
                     stageX<4>(xcA, p.latent + (size_t)t * Dn, Tn * Dn, k0, bg); klen = 64; }
        else       { stageW48<3>(wT0, W, Dn + Sn, k0, os);
                     stageX<3>(xcA, p.st, Sn, 0, bg); klen = 32; }
      } else {
        stageW48<4>(wT0, W, Hn, k0, os);
        stageX<4>(xcA, p.h0, Hn, k0, bg); klen = 64;
      }
      __syncthreads();
      const int q = klen >> 2;
      ghAccum(acc, wT0, xcA, v, wp * q, wp * q + q);
      __syncthreads();
    }
    {
      const int rp = v >> 3, jp = v & 7;
      #pragma unroll
      for (int g = 0; g < 3; g++) {
        part[wp][rp * 2    ][g * 16 + jp * 2    ] = acc[g * 4 + 0];
        part[wp][rp * 2    ][g * 16 + jp * 2 + 1] = acc[g * 4 + 1];
        part[wp][rp * 2 + 1][g * 16 + jp * 2    ] = acc[g * 4 + 2];
        part[wp][rp * 2 + 1][g * 16 + jp * 2 + 1] = acc[g * 4 + 3];
      }
    }
    __syncthreads();
    {
      const int r = TID >> 4, j = TID & 15;
      const int b = bg * BC + r; const int col = os * JH + j;
      const float ig0 = part[0][r][j] + part[1][r][j] + part[2][r][j] + part[3][r][j] + bih[col];
      const float ig1 = part[0][r][16 + j] + part[1][r][16 + j] + part[2][r][16 + j] + part[3][r][16 + j] + bih[Hn + col];
      const float ig2 = part[0][r][32 + j] + part[1][r][32 + j] + part[2][r][32 + j] + part[3][r][32 + j] + bih[2 * Hn + col];
      const float hr = ghL[r][j], hz = ghL[r][16 + j], hn = ghL[r][32 + j];
      const float rg = 1.f / (1.f + expf(-(ig0 + hr)));
      const float zg = 1.f / (1.f + expf(-(ig1 + hz)));
      const float ng = tanhf(ig2 + rg * hn);
      const float hold = hbuf[b * Hn + col];
      hbuf[b * Hn + col] = (1.f - zg) * ng + zg * hold;
    }
    __syncthreads();
  };

  phaseE(0);
  team_bar(&bars[bar_i++]);

  for (int t = 0; t < Tn; t++) {
    phaseB(t);
    team_bar(&bars[bar_i++]);
    phaseGRU(p.wih0, p.bih0, ghA, p.h0, true, t);
    team_bar(&bars[bar_i++]);
    phaseGRU(p.wih1, p.bih1, ghB, p.h1, false, t);
    team_bar(&bars[bar_i++]);
    phaseE(t + 1);
    team_bar(&bars[bar_i++]);
  }

  // ---- epilogue: prior head for t=255 + h_final ----
  {
    const int ll = TID & 127;
    const int r_ = ll & 31, cc_ = (ll >> 5) & 1, ks_ = ll >> 6;
    if (wv >= 6) {
      const float d = dotChunk(p.qh + (size_t)(bg * BC + r_) * Hn,
                               p.wprior2 + (size_t)(os + 32 * cc_) * Hn, ks_ * 256, 256);
      prq[cc_][ks_][r_] = d;
    }
    __syncthreads();
    if (TID >= 64 && TID < 128) {
      const int u = TID - 64; const int r = u & 31, cc = u >> 5;
      const float val = prq[cc][0][r] + prq[cc][1][r] + p.bprior2[os + 32 * cc];
      p.out[(cc ? OFF_PRLV : OFF_PRM) + (size_t)(bg * BC + r) * (Tn * Sn) + 255 * Sn + os] = val;
    }
    const int r = TID >> 4, j = TID & 15;
    const int b = bg * BC + r; const int col = os * JH + j;
    p.out[OFF_HF + b * Hn + col] = p.h0[b * Hn + col];
    p.out[OFF_HF + Bn * Hn + b * Hn + col] = p.h1[b * Hn + col];
  }
}

}  // namespace

extern "C" void kernel_launch(void* const* d_in, const int* in_sizes, int n_in,
                              void* d_out, int out_size, void* d_ws, size_t ws_size,
                              hipStream_t stream) {
  (void)in_sizes; (void)n_in; (void)out_size; (void)ws_size;
  float* ws = (float*)d_ws;
  P p;
  p.latent  = (const float*)d_in[0];
  p.hidden  = (const float*)d_in[1];
  p.eps     = (const float*)d_in[2];
  p.wih0    = (const float*)d_in[3];
  p.whh0    = (const float*)d_in[4];
  p.bih0    = (const float*)d_in[5];
  p.bhh0    = (const float*)d_in[6];
  p.wih1    = (const float*)d_in[7];
  p.whh1    = (const float*)d_in[8];
  p.bih1    = (const float*)d_in[9];
  p.bhh1    = (const float*)d_in[10];
  p.wpost1  = (const float*)d_in[11];
  p.bpost1  = (const float*)d_in[12];
  p.wpost2  = (const float*)d_in[13];
  p.bpost2  = (const float*)d_in[14];
  p.wprior1 = (const float*)d_in[15];
  p.bprior1 = (const float*)d_in[16];
  p.wprior2 = (const float*)d_in[17];
  p.bprior2 = (const float*)d_in[18];
  p.out = (float*)d_out;
  // workspace: h0 h1 ph qh stoch | barrier slots  (~2.1 MB total)
  p.h0 = ws;
  p.h1 = ws + 131072;
  p.ph = ws + 262144;
  p.qh = ws + 393216;
  p.st = ws + 524288;
  p.bars = (unsigned*)(ws + 532480);

  // Zero barrier slots each call (capturable memset node) -> no reliance on 0xAA poison.
  hipMemsetAsync(p.bars, 0, 8 * BARS_PER_TEAM * sizeof(unsigned), stream);

  void* args[] = { &p };
  hipLaunchCooperativeKernel((void*)rssm_kernel, dim3(256), dim3(512), args, 0, stream);
}